// Round 9
// baseline (481.558 us; speedup 1.0000x reference)
//
#include <hip/hip_runtime.h>

// MultiHeadedAttention: B=32 L=1024 D=512 H=8 DK=64 W=5
// 5 launches: tcast2 -> proj3 -> localmix2 -> attn -> gemmout.
// GEMM: BARRIER-FREE wave-private structure. Wave = 32 rows x 128 cols.
// Each wave reg-stages its own A band (32x32) into its own LDS quadrant
// (global->VGPR->cvtpk->ds_write, 2 iters ahead); B-frags direct from
// L2-resident weight, register ping-pong (1 iter ahead). All deps wave-local:
// NO __syncthreads anywhere, waves free-run, TLP hides latency.
// Attn: swapped-QKT in-register P, no-max base-2 softmax, dbuf LDS (R7).

typedef __attribute__((ext_vector_type(8))) short bf16x8;
typedef __attribute__((ext_vector_type(4))) float f32x4;

#define MFMA16(a, b, c) __builtin_amdgcn_mfma_f32_16x16x32_bf16((a), (b), (c), 0, 0, 0)

static __device__ __forceinline__ float bf2f(unsigned short u) {
  union { unsigned int i; float f; } v; v.i = ((unsigned int)u) << 16; return v.f;
}
static __device__ __forceinline__ unsigned short f2b(float f) {
  union { float fv; unsigned int i; } v; v.fv = f;
  unsigned int u = v.i;
  return (unsigned short)((u + 0x7fffu + ((u >> 16) & 1u)) >> 16);
}
static __device__ __forceinline__ unsigned int cvtpk(float lo, float hi) {
  unsigned int r;
  asm("v_cvt_pk_bf16_f32 %0, %1, %2" : "=v"(r) : "v"(lo), "v"(hi));
  return r;
}
static __device__ __forceinline__ void barrier_lgkm() {
  asm volatile("s_waitcnt lgkmcnt(0)" ::: "memory");
  __builtin_amdgcn_s_barrier();
  __builtin_amdgcn_sched_barrier(0);
}

// ---------------------------------------------------------------- tcast ----
__global__ __launch_bounds__(256) void tcast2_k(const float* __restrict__ s0,
                                                unsigned short* __restrict__ d0,
                                                const float* __restrict__ s1,
                                                unsigned short* __restrict__ d1) {
  int i = blockIdx.x * 256 + threadIdx.x;
  const float* s = s0;
  unsigned short* d = d0;
  if (i >= 262144) { i -= 262144; s = s1; d = d1; }
  int k = i >> 9, n = i & 511;
  d[(size_t)n * 512 + k] = f2b(s[(size_t)k * 512 + n]);
}

// ------------------------------------------------- wave-private gemm body ----
// Per-wave LDS tile [32 rows][32 k] bf16 (2KB), double-buffered; granule
// (16B) swizzle g' = g ^ ((row>>1)&3) -> even bank spread on b128 r/w.
// A(j) regs live in set j&1; B(j) regs in slot j&1.
template <int AMODE, int OUTMODE>
__device__ __forceinline__ void gemm_wp(const void* __restrict__ A_,
                                        const unsigned short* __restrict__ BT,
                                        const float* __restrict__ bias,
                                        void* __restrict__ out_, int bm, int bn) {
  __shared__ unsigned short As[4][2][32 * 32];  // [wave][buf] 16KB total
  const int tid = threadIdx.x;
  const int w = tid >> 6, l = tid & 63;
  const int lg = l >> 4, lr = l & 15;
  const int rowbase = bm * 128 + w * 32;
  const int colbase = bn * 128;

  // staging map: lane -> row l>>1, k-half l&1 (granules 2ks, 2ks+1)
  const int srow = l >> 1, ks = l & 1;
  const int sswz = (l >> 2) & 3;                 // (srow>>1)&3
  const int g0 = (2 * ks) ^ sswz, g1 = (2 * ks + 1) ^ sswz;
  const int rswz = (lr >> 1) & 3;                // read-side swizzle

  f32x4 acc[2][8];
#pragma unroll
  for (int m = 0; m < 2; ++m)
#pragma unroll
    for (int n = 0; n < 8; ++n) acc[m][n] = (f32x4){0.f, 0.f, 0.f, 0.f};

  float4 fa0[4], fa1[4];   // AMODE 0 A-stage sets
  uint4 ba0[2], ba1[2];    // AMODE 1 A-stage sets
  bf16x8 br0[8], br1[8];   // B ping-pong

  auto loadAf = [&](int kt, float4* d) {
    const float* p = (const float*)A_ + (size_t)(rowbase + srow) * 512 + kt * 32 + ks * 16;
    d[0] = ((const float4*)p)[0]; d[1] = ((const float4*)p)[1];
    d[2] = ((const float4*)p)[2]; d[3] = ((const float4*)p)[3];
  };
  auto loadAb = [&](int kt, uint4* d) {
    const unsigned short* p = (const unsigned short*)A_ + (size_t)(rowbase + srow) * 512 + kt * 32 + ks * 16;
    d[0] = ((const uint4*)p)[0]; d[1] = ((const uint4*)p)[1];
  };
  auto loadB = [&](int kt, bf16x8* d) {
#pragma unroll
    for (int n = 0; n < 8; ++n)
      d[n] = *(const bf16x8*)(BT + (size_t)(colbase + n * 16 + lr) * 512 + kt * 32 + lg * 8);
  };
  auto writeAf = [&](int buf, const float4* d) {
    uint4 u0, u1;
    u0.x = cvtpk(d[0].x, d[0].y); u0.y = cvtpk(d[0].z, d[0].w);
    u0.z = cvtpk(d[1].x, d[1].y); u0.w = cvtpk(d[1].z, d[1].w);
    u1.x = cvtpk(d[2].x, d[2].y); u1.y = cvtpk(d[2].z, d[2].w);
    u1.z = cvtpk(d[3].x, d[3].y); u1.w = cvtpk(d[3].z, d[3].w);
    *(uint4*)&As[w][buf][srow * 32 + g0 * 8] = u0;
    *(uint4*)&As[w][buf][srow * 32 + g1 * 8] = u1;
  };
  auto writeAb = [&](int buf, const uint4* d) {
    *(uint4*)&As[w][buf][srow * 32 + g0 * 8] = d[0];
    *(uint4*)&As[w][buf][srow * 32 + g1 * 8] = d[1];
  };

  // prologue: A(0)->set0 (staged to buf0), A(1)->set1, B(0)->slot0
  if constexpr (AMODE == 0) { loadAf(0, fa0); } else { loadAb(0, ba0); }
  loadB(0, br0);
  if constexpr (AMODE == 0) { loadAf(1, fa1); } else { loadAb(1, ba1); }
  if constexpr (AMODE == 0) writeAf(0, fa0); else writeAb(0, ba0);

#pragma unroll
  for (int kt = 0; kt < 16; ++kt) {
    const int cur = kt & 1;
    // prefetch A(kt+2) into the set just freed (set kt&1)
    if (kt < 14) {
      if constexpr (AMODE == 0) { if (cur == 0) loadAf(kt + 2, fa0); else loadAf(kt + 2, fa1); }
      else                      { if (cur == 0) loadAb(kt + 2, ba0); else loadAb(kt + 2, ba1); }
    }
    // prefetch B(kt+1) into the other slot
    if (kt < 15) { if (cur == 0) loadB(kt + 1, br1); else loadB(kt + 1, br0); }
    // A frags for kt from own LDS buf
    bf16x8 af[2];
#pragma unroll
    for (int m = 0; m < 2; ++m) {
      const int r = m * 16 + lr;
      af[m] = *(const bf16x8*)&As[w][cur][r * 32 + ((lg ^ rswz) << 3)];
    }
    const bf16x8* bcur = cur == 0 ? br0 : br1;
#pragma unroll
    for (int m = 0; m < 2; ++m)
#pragma unroll
      for (int n = 0; n < 8; ++n) acc[m][n] = MFMA16(af[m], bcur[n], acc[m][n]);
    // stage A(kt+1) (regs loaded last iter) into buf kt+1
    if (kt < 15) {
      if constexpr (AMODE == 0) { if (cur == 0) writeAf(1, fa1); else writeAf(0, fa0); }
      else                      { if (cur == 0) writeAb(1, ba1); else writeAb(0, ba0); }
    }
  }

#pragma unroll
  for (int m = 0; m < 2; ++m)
#pragma unroll
    for (int n = 0; n < 8; ++n) {
      const int grow0 = rowbase + m * 16 + 4 * lg;
      const int gcol = colbase + n * 16 + lr;
      const float bs = bias[gcol];
#pragma unroll
      for (int r = 0; r < 4; ++r) {
        float v = acc[m][n][r] + bs;
        if constexpr (OUTMODE == 0)
          ((unsigned short*)out_)[(size_t)(grow0 + r) * 512 + gcol] = f2b(v);
        else
          ((float*)out_)[(size_t)(grow0 + r) * 512 + gcol] = v;
      }
    }
}

// Fused q/k/v projection: 3072 blocks, XCD-swizzled (3072%8==0, bijective).
__global__ __launch_bounds__(256) void proj3_k(const float* __restrict__ q,
                                               const float* __restrict__ k,
                                               const float* __restrict__ v,
                                               const unsigned short* __restrict__ W0T,
                                               const float* __restrict__ b0,
                                               unsigned short* __restrict__ Pq,
                                               unsigned short* __restrict__ Pk,
                                               unsigned short* __restrict__ Pv) {
  const int wg = (blockIdx.x & 7) * 384 + (blockIdx.x >> 3);
  const int t = wg >> 10, rem = wg & 1023;
  const float* A = t == 0 ? q : t == 1 ? k : v;
  unsigned short* O = t == 0 ? Pq : t == 1 ? Pk : Pv;
  gemm_wp<0, 0>(A, W0T, b0, O, rem >> 2, rem & 3);
}

__global__ __launch_bounds__(256) void gemmout_k(const unsigned short* __restrict__ A,
                                                 const unsigned short* __restrict__ WoT,
                                                 const float* __restrict__ bout,
                                                 float* __restrict__ out) {
  const int wg = (blockIdx.x & 7) * 128 + (blockIdx.x >> 3);
  gemm_wp<1, 1>(A, WoT, bout, out, wg >> 2, wg & 3);
}

// ------------------------------------------------------------- localmix ----
__global__ __launch_bounds__(256) void localmix2_k(const unsigned short* __restrict__ Pq,
                                                   const unsigned short* __restrict__ Pk,
                                                   const float* __restrict__ b0,
                                                   unsigned short* __restrict__ Qm,
                                                   unsigned short* __restrict__ Km) {
  const int w = threadIdx.x >> 6, lane = threadIdx.x & 63;
  const int pp = blockIdx.x * 4 + w;
  const unsigned short* P;
  unsigned short* out;
  float outscale;
  int p;
  if (pp < 32768) { P = Pq; out = Qm; outscale = 0.18033688011112042f; p = pp; }
  else            { P = Pk; out = Km; outscale = 1.0f; p = pp - 32768; }
  const int l = p & 1023;
  const int d0 = lane * 8;

  float win[5][8];
#pragma unroll
  for (int j = 0; j < 5; ++j) {
    const int src = l - 4 + j;
    if (src >= 0) {
      const uint4 v = *(const uint4*)(P + (size_t)(p - 4 + j) * 512 + d0);
      const unsigned short* u = (const unsigned short*)&v;
#pragma unroll
      for (int i = 0; i < 8; ++i) win[j][i] = bf2f(u[i]);
    } else {
      const float4 f0 = *(const float4*)(b0 + d0);
      const float4 f1 = *(const float4*)(b0 + d0 + 4);
      win[j][0] = f0.x; win[j][1] = f0.y; win[j][2] = f0.z; win[j][3] = f0.w;
      win[j][4] = f1.x; win[j][5] = f1.y; win[j][6] = f1.z; win[j][7] = f1.w;
    }
  }
  float s[5];
#pragma unroll
  for (int j = 0; j < 5; ++j) {
    float t = 0.f;
#pragma unroll
    for (int i = 0; i < 8; ++i) t += win[4][i] * win[j][i];
    s[j] = t;
  }
#pragma unroll
  for (int off = 1; off < 64; off <<= 1)
#pragma unroll
    for (int j = 0; j < 5; ++j) s[j] += __shfl_xor(s[j], off, 64);
  const float sc = 0.04419417382415922f;
  float mx = -1e30f;
#pragma unroll
  for (int j = 0; j < 5; ++j) { s[j] *= sc; mx = fmaxf(mx, s[j]); }
  float e[5], sum = 0.f;
#pragma unroll
  for (int j = 0; j < 5; ++j) { e[j] = __expf(s[j] - mx); sum += e[j]; }
  const float inv = 1.f / sum;
  __attribute__((ext_vector_type(8))) unsigned short o;
#pragma unroll
  for (int i = 0; i < 8; ++i) {
    float a = 0.f;
#pragma unroll
    for (int j = 0; j < 5; ++j) a += e[j] * win[j][i];
    o[i] = f2b(a * inv * outscale);
  }
  *(__attribute__((ext_vector_type(8))) unsigned short*)(out + (size_t)p * 512 + d0) = o;
}

// ----------------------------------------------------------------- attn ----
__global__ __launch_bounds__(256) void attn_k(const unsigned short* __restrict__ Q,
                                              const unsigned short* __restrict__ K,
                                              const unsigned short* __restrict__ V,
                                              unsigned short* __restrict__ AO) {
  __shared__ unsigned short Ks[2][64 * 64];
  __shared__ unsigned short Vt[2][64 * 64];
  const int tid = threadIdx.x;
  const int w = tid >> 6, l = tid & 63;
  const int lg = l >> 4, lr = l & 15;
  const int wg = (blockIdx.x & 7) * 256 + (blockIdx.x >> 3);
  const int qt = wg & 7, bh = wg >> 3;
  const int h = bh & 7, b = bh >> 3;
  const size_t base = (size_t)(b * 1024) * 512 + h * 64;
  const unsigned short* Qb = Q + base + (size_t)(qt * 128) * 512;
  const unsigned short* Kb = K + base;
  const unsigned short* Vb = V + base;

  bf16x8 qf[2][2];
#pragma unroll
  for (int rb = 0; rb < 2; ++rb)
#pragma unroll
    for (int ks = 0; ks < 2; ++ks)
      qf[rb][ks] = *(const bf16x8*)(Qb + (size_t)(w * 32 + rb * 16 + lr) * 512 + ks * 32 + lg * 8);

  f32x4 acc[2][4];
#pragma unroll
  for (int rb = 0; rb < 2; ++rb)
#pragma unroll
    for (int nb = 0; nb < 4; ++nb) acc[rb][nb] = (f32x4){0.f, 0.f, 0.f, 0.f};
  float lrun[2] = {0.f, 0.f};

  const int sk_row = tid >> 2, sk_seg = tid & 3;
  const int sv_key = tid & 63, sv_d0 = (tid >> 6) * 16;
  const int vpos = (sv_key & 32) + ((sv_key >> 2) & 3) * 8 + ((sv_key >> 4) & 1) * 4 + (sv_key & 3);
  const int vpg = vpos >> 3, vpw = vpos & 7;
  const int r7 = sk_row & 7;

  uint4 kr0, kr1, vr0, vr1;
  auto loadT = [&](int t) {
    const uint4* ksrc = (const uint4*)(Kb + (size_t)(t * 64 + sk_row) * 512 + sk_seg * 16);
    kr0 = ksrc[0]; kr1 = ksrc[1];
    const uint4* vsrc = (const uint4*)(Vb + (size_t)(t * 64 + sv_key) * 512 + sv_d0);
    vr0 = vsrc[0]; vr1 = vsrc[1];
  };
  auto writeT = [&](int bufi) {
    unsigned short* kd = Ks[bufi];
    unsigned short* vd = Vt[bufi];
    *(uint4*)&kd[sk_row * 64 + (((2 * sk_seg) ^ r7) << 3)] = kr0;
    *(uint4*)&kd[sk_row * 64 + (((2 * sk_seg + 1) ^ r7) << 3)] = kr1;
    const unsigned short* u0 = (const unsigned short*)&vr0;
    const unsigned short* u1 = (const unsigned short*)&vr1;
#pragma unroll
    for (int j = 0; j < 8; ++j) {
      vd[(sv_d0 + j) * 64 + (((vpg ^ j) << 3) | vpw)] = u0[j];
      vd[(sv_d0 + 8 + j) * 64 + (((vpg ^ j) << 3) | vpw)] = u1[j];
    }
  };

  loadT(0);
  writeT(0);
  loadT(1);
  barrier_lgkm();

  const int swz0 = (lg ^ (lr & 7)) << 3, swz1 = ((4 + lg) ^ (lr & 7)) << 3;

  for (int it = 0; it < 16; ++it) {
    const int cur = it & 1;
    f32x4 sf[2][4];
    __builtin_amdgcn_s_setprio(1);
#pragma unroll
    for (int kb = 0; kb < 4; ++kb) {
      const int krow = (kb * 16 + lr) * 64;
      bf16x8 kf0 = *(const bf16x8*)&Ks[cur][krow + swz0];
      bf16x8 kf1 = *(const bf16x8*)&Ks[cur][krow + swz1];
#pragma unroll
      for (int rb = 0; rb < 2; ++rb) {
        f32x4 z = (f32x4){0.f, 0.f, 0.f, 0.f};
        z = MFMA16(kf0, qf[rb][0], z);
        z = MFMA16(kf1, qf[rb][1], z);
        sf[rb][kb] = z;
      }
    }
    __builtin_amdgcn_s_setprio(0);

    if (it < 15) writeT((it + 1) & 1);
    if (it < 14) loadT(it + 2);

#pragma unroll
    for (int rb = 0; rb < 2; ++rb) {
#pragma unroll
      for (int kb = 0; kb < 4; ++kb)
#pragma unroll
        for (int r = 0; r < 4; ++r)
          sf[rb][kb][r] = __builtin_amdgcn_exp2f(sf[rb][kb][r]);
      float s0 = (sf[rb][0][0] + sf[rb][0][1]) + (sf[rb][0][2] + sf[rb][0][3]);
      float s1 = (sf[rb][1][0] + sf[rb][1][1]) + (sf[rb][1][2] + sf[rb][1][3]);
      float s2 = (sf[rb][2][0] + sf[rb][2][1]) + (sf[rb][2][2] + sf[rb][2][3]);
      float s3 = (sf[rb][3][0] + sf[rb][3][1]) + (sf[rb][3][2] + sf[rb][3][3]);
      float t = (s0 + s1) + (s2 + s3);
      t += __shfl_xor(t, 16, 64);
      t += __shfl_xor(t, 32, 64);
      lrun[rb] += t;
    }

    union { uint4 d; bf16x8 v; } pa[2][2];
#pragma unroll
    for (int rb = 0; rb < 2; ++rb)
#pragma unroll
      for (int t2 = 0; t2 < 2; ++t2) {
        pa[rb][t2].d.x = cvtpk(sf[rb][2 * t2][0], sf[rb][2 * t2][1]);
        pa[rb][t2].d.y = cvtpk(sf[rb][2 * t2][2], sf[rb][2 * t2][3]);
        pa[rb][t2].d.z = cvtpk(sf[rb][2 * t2 + 1][0], sf[rb][2 * t2 + 1][1]);
        pa[rb][t2].d.w = cvtpk(sf[rb][2 * t2 + 1][2], sf[rb][2 * t2 + 1][3]);
      }

    __builtin_amdgcn_s_setprio(1);
#pragma unroll
    for (int t2 = 0; t2 < 2; ++t2) {
      bf16x8 vf[4];
#pragma unroll
      for (int nb = 0; nb < 4; ++nb) {
        const int vrow = (nb * 16 + lr) * 64;
        vf[nb] = *(const bf16x8*)&Vt[cur][vrow + (((4 * t2 + lg) ^ (lr & 7)) << 3)];
      }
#pragma unroll
      for (int rb = 0; rb < 2; ++rb)
#pragma unroll
        for (int nb = 0; nb < 4; ++nb) acc[rb][nb] = MFMA16(pa[rb][t2].v, vf[nb], acc[rb][nb]);
    }
    __builtin_amdgcn_s_setprio(0);
    if (it < 15) barrier_lgkm();
  }

#pragma unroll
  for (int rb = 0; rb < 2; ++rb) {
    const float rec = 1.f / lrun[rb];
    float lv[4];
#pragma unroll
    for (int r = 0; r < 4; ++r) lv[r] = __shfl(rec, lg * 4 + r, 64);
#pragma unroll
    for (int nb = 0; nb < 4; ++nb) {
      const int gcol = nb * 16 + lr;
#pragma unroll
      for (int r = 0; r < 4; ++r) {
        const int grow = qt * 128 + w * 32 + rb * 16 + 4 * lg + r;
        AO[base + (size_t)grow * 512 + gcol] = f2b(acc[rb][nb][r] * lv[r]);
      }
    }
  }
}

// -------------------------------------------------------------- launch -----
extern "C" void kernel_launch(void* const* d_in, const int* in_sizes, int n_in,
                              void* d_out, int out_size, void* d_ws, size_t ws_size,
                              hipStream_t stream) {
  const float* query = (const float*)d_in[0];
  const float* key   = (const float*)d_in[1];
  const float* value = (const float*)d_in[2];
  const float* W0    = (const float*)d_in[3];
  const float* b0    = (const float*)d_in[4];
  const float* Wout  = (const float*)d_in[5];
  const float* bout  = (const float*)d_in[6];
  float* out = (float*)d_out;

  char* ws = (char*)d_ws;
  const size_t PSZ = (size_t)32768 * 512 * 2;
  unsigned short* Pq  = (unsigned short*)(ws);            // later reused as AO
  unsigned short* Pk  = (unsigned short*)(ws + PSZ);
  unsigned short* Pv  = (unsigned short*)(ws + 2 * PSZ);
  unsigned short* Qm  = (unsigned short*)(ws + 3 * PSZ);
  unsigned short* Km  = (unsigned short*)(ws + 4 * PSZ);
  unsigned short* W0T = (unsigned short*)(ws + 5 * PSZ);
  unsigned short* WoT = (unsigned short*)(ws + 5 * PSZ + 524288);

  tcast2_k<<<2048, 256, 0, stream>>>(W0, W0T, Wout, WoT);
  proj3_k<<<3072, 256, 0, stream>>>(query, key, value, W0T, b0, Pq, Pk, Pv);
  localmix2_k<<<16384, 256, 0, stream>>>(Pq, Pk, b0, Qm, Km);
  attn_k<<<2048, 256, 0, stream>>>(Qm, Km, Pv, Pq /*AO*/);
  gemmout_k<<<1024, 256, 0, stream>>>(Pq, WoT, bout, out);
}

// Round 10
// 289.171 us; speedup vs baseline: 1.6653x; 1.6653x over previous
//
#include <hip/hip_runtime.h>

// MultiHeadedAttention: B=32 L=1024 D=512 H=8 DK=64 W=5
// 5 launches: tcast2 -> proj3 -> localmix2 -> attn -> gemmout.
// GEMM: 256x256 tile, 8 waves (512 thr), BK=64, double-buffered, 2-phase
// (m230/m248 recipe): stage(t+1) issued first, ds_read+MFMA covers latency,
// one __syncthreads per K-tile. B via global_load_lds (pre-swizzled source);
// A reg-staged with in-reg f32->bf16. Granule-XOR swizzle both tiles.
// Attn: swapped-QKT in-register P, no-max base-2 softmax, dbuf LDS (R7).

typedef __attribute__((ext_vector_type(8))) short bf16x8;
typedef __attribute__((ext_vector_type(4))) float f32x4;

#define MFMA16(a, b, c) __builtin_amdgcn_mfma_f32_16x16x32_bf16((a), (b), (c), 0, 0, 0)

static __device__ __forceinline__ float bf2f(unsigned short u) {
  union { unsigned int i; float f; } v; v.i = ((unsigned int)u) << 16; return v.f;
}
static __device__ __forceinline__ unsigned short f2b(float f) {
  union { float fv; unsigned int i; } v; v.fv = f;
  unsigned int u = v.i;
  return (unsigned short)((u + 0x7fffu + ((u >> 16) & 1u)) >> 16);
}
static __device__ __forceinline__ unsigned int cvtpk(float lo, float hi) {
  unsigned int r;
  asm("v_cvt_pk_bf16_f32 %0, %1, %2" : "=v"(r) : "v"(lo), "v"(hi));
  return r;
}
static __device__ __forceinline__ void glds16(const void* g, void* l) {
  __builtin_amdgcn_global_load_lds(
      (const __attribute__((address_space(1))) unsigned int*)g,
      (__attribute__((address_space(3))) unsigned int*)l, 16, 0, 0);
}
static __device__ __forceinline__ void barrier_lgkm() {
  asm volatile("s_waitcnt lgkmcnt(0)" ::: "memory");
  __builtin_amdgcn_s_barrier();
  __builtin_amdgcn_sched_barrier(0);
}

// ---------------------------------------------------------------- tcast ----
__global__ __launch_bounds__(256) void tcast2_k(const float* __restrict__ s0,
                                                unsigned short* __restrict__ d0,
                                                const float* __restrict__ s1,
                                                unsigned short* __restrict__ d1) {
  int i = blockIdx.x * 256 + threadIdx.x;
  const float* s = s0;
  unsigned short* d = d0;
  if (i >= 262144) { i -= 262144; s = s1; d = d1; }
  int k = i >> 9, n = i & 511;
  d[(size_t)n * 512 + k] = f2b(s[(size_t)k * 512 + n]);
}

// --------------------------------------------------- 256x256 gemm body ----
// LDS: As/Bs [2][256 rows][64 k] bf16 (32KB each buf). Granule (16B) swizzle
// slot = g ^ (row&7) everywhere (write via pre-swizzled source / reg addr,
// read with matching XOR). 8 waves: wr=w>>2 (128-row band), wc=w&3 (64 cols).
template <int AMODE, int OUTMODE>
__device__ __forceinline__ void gemm256(const void* __restrict__ A_,
                                        const unsigned short* __restrict__ BT,
                                        const float* __restrict__ bias,
                                        void* __restrict__ out_, int bm, int bn) {
  __shared__ unsigned short As[2][256 * 64];
  __shared__ unsigned short Bs[2][256 * 64];
  const int tid = threadIdx.x;  // 0..511
  const int w = tid >> 6, l = tid & 63;
  const int lg = l >> 4, lr = l & 15;
  const int wr = w >> 2, wc = w & 3;
  const int rowbase = bm * 256;
  const int colbase = bn * 256;

  // A staging map: thread -> row ar (0..255), k-half kh (granules 4kh..4kh+3)
  const int ar = tid >> 1, kh = tid & 1;
  const int arw = ar & 7;

  f32x4 acc[8][4];
#pragma unroll
  for (int mi = 0; mi < 8; ++mi)
#pragma unroll
    for (int ni = 0; ni < 4; ++ni) acc[mi][ni] = (f32x4){0.f, 0.f, 0.f, 0.f};

  float4 fa[8];  // AMODE 0 stage regs (32 f32)
  uint4 ba[4];   // AMODE 1 stage regs

  auto loadA = [&](int t) {
    if constexpr (AMODE == 0) {
      const float* p = (const float*)A_ + (size_t)(rowbase + ar) * 512 + t * 64 + kh * 32;
#pragma unroll
      for (int j = 0; j < 8; ++j) fa[j] = ((const float4*)p)[j];
    } else {
      const unsigned short* p = (const unsigned short*)A_ + (size_t)(rowbase + ar) * 512 + t * 64 + kh * 32;
#pragma unroll
      for (int j = 0; j < 4; ++j) ba[j] = ((const uint4*)p)[j];
    }
  };
  auto writeA = [&](int buf) {
    unsigned short* dst = &As[buf][ar * 64];
#pragma unroll
    for (int j = 0; j < 4; ++j) {
      const int g = 4 * kh + j;
      uint4 u;
      if constexpr (AMODE == 0) {
        u.x = cvtpk(fa[2 * j].x, fa[2 * j].y);
        u.y = cvtpk(fa[2 * j].z, fa[2 * j].w);
        u.z = cvtpk(fa[2 * j + 1].x, fa[2 * j + 1].y);
        u.w = cvtpk(fa[2 * j + 1].z, fa[2 * j + 1].w);
      } else {
        u = ba[j];
      }
      *(uint4*)&dst[((g ^ arw) << 3)] = u;
    }
  };
  auto stageB = [&](int t, int buf) {
    const unsigned short* Bt = BT + t * 64;
#pragma unroll
    for (int j = 0; j < 4; ++j) {
      const int jr = j * 64 + w * 8 + (l >> 3);
      const int g = (l & 7) ^ (jr & 7);
      glds16(Bt + (size_t)(colbase + jr) * 512 + g * 8,
             &Bs[buf][(j * 64 + w * 8) * 64]);
    }
  };

  // prologue: tile 0 fully staged
  loadA(0);
  stageB(0, 0);
  writeA(0);        // waits its own A-loads (compiler vmcnt)
  __syncthreads();  // drains B gloads + lgkm

  for (int t = 0; t < 8; ++t) {
    const int cur = t & 1;
    // issue next-tile loads FIRST (ds_read+MFMA below covers their latency)
    if (t < 7) {
      loadA(t + 1);
      stageB(t + 1, cur ^ 1);
    }
    // compute tile t from buf[cur]
#pragma unroll
    for (int ks = 0; ks < 2; ++ks) {
      bf16x8 af[8], bf[4];
#pragma unroll
      for (int ni = 0; ni < 4; ++ni) {
        const int c = wc * 64 + ni * 16 + lr;
        bf[ni] = *(const bf16x8*)&Bs[cur][c * 64 + (((4 * ks + lg) ^ (c & 7)) << 3)];
      }
#pragma unroll
      for (int mi = 0; mi < 8; ++mi) {
        const int r = wr * 128 + mi * 16 + lr;
        af[mi] = *(const bf16x8*)&As[cur][r * 64 + (((4 * ks + lg) ^ (r & 7)) << 3)];
      }
      __builtin_amdgcn_s_setprio(1);
#pragma unroll
      for (int mi = 0; mi < 8; ++mi)
#pragma unroll
        for (int ni = 0; ni < 4; ++ni) acc[mi][ni] = MFMA16(af[mi], bf[ni], acc[mi][ni]);
      __builtin_amdgcn_s_setprio(0);
    }
    if (t < 7) {
      writeA(cur ^ 1);   // A regs loaded above; vmcnt wait mostly covered
      __syncthreads();   // drains B gloads (vmcnt0) + A ds_writes
    }
  }

#pragma unroll
  for (int mi = 0; mi < 8; ++mi)
#pragma unroll
    for (int ni = 0; ni < 4; ++ni) {
      const int grow0 = rowbase + wr * 128 + mi * 16 + 4 * lg;
      const int gcol = colbase + wc * 64 + ni * 16 + lr;
      const float bs = bias[gcol];
#pragma unroll
      for (int r = 0; r < 4; ++r) {
        float v = acc[mi][ni][r] + bs;
        if constexpr (OUTMODE == 0)
          ((unsigned short*)out_)[(size_t)(grow0 + r) * 512 + gcol] = f2b(v);
        else
          ((float*)out_)[(size_t)(grow0 + r) * 512 + gcol] = v;
      }
    }
}

// Fused q/k/v projection: 768 blocks (256 per tensor), XCD-swizzled.
__global__ __launch_bounds__(512) void proj3_k(const float* __restrict__ q,
                                               const float* __restrict__ k,
                                               const float* __restrict__ v,
                                               const unsigned short* __restrict__ W0T,
                                               const float* __restrict__ b0,
                                               unsigned short* __restrict__ Pq,
                                               unsigned short* __restrict__ Pk,
                                               unsigned short* __restrict__ Pv) {
  const int wg = (blockIdx.x & 7) * 96 + (blockIdx.x >> 3);
  const int t = wg >> 8, rem = wg & 255;
  const float* A = t == 0 ? q : t == 1 ? k : v;
  unsigned short* O = t == 0 ? Pq : t == 1 ? Pk : Pv;
  gemm256<0, 0>(A, W0T, b0, O, rem >> 1, rem & 1);
}

__global__ __launch_bounds__(512) void gemmout_k(const unsigned short* __restrict__ A,
                                                 const unsigned short* __restrict__ WoT,
                                                 const float* __restrict__ bout,
                                                 float* __restrict__ out) {
  const int wg = (blockIdx.x & 7) * 32 + (blockIdx.x >> 3);
  gemm256<1, 1>(A, WoT, bout, out, wg >> 1, wg & 1);
}

// ------------------------------------------------------------- localmix ----
__global__ __launch_bounds__(256) void localmix2_k(const unsigned short* __restrict__ Pq,
                                                   const unsigned short* __restrict__ Pk,
                                                   const float* __restrict__ b0,
                                                   unsigned short* __restrict__ Qm,
                                                   unsigned short* __restrict__ Km) {
  const int w = threadIdx.x >> 6, lane = threadIdx.x & 63;
  const int pp = blockIdx.x * 4 + w;
  const unsigned short* P;
  unsigned short* out;
  float outscale;
  int p;
  if (pp < 32768) { P = Pq; out = Qm; outscale = 0.18033688011112042f; p = pp; }
  else            { P = Pk; out = Km; outscale = 1.0f; p = pp - 32768; }
  const int l = p & 1023;
  const int d0 = lane * 8;

  float win[5][8];
#pragma unroll
  for (int j = 0; j < 5; ++j) {
    const int src = l - 4 + j;
    if (src >= 0) {
      const uint4 v = *(const uint4*)(P + (size_t)(p - 4 + j) * 512 + d0);
      const unsigned short* u = (const unsigned short*)&v;
#pragma unroll
      for (int i = 0; i < 8; ++i) win[j][i] = bf2f(u[i]);
    } else {
      const float4 f0 = *(const float4*)(b0 + d0);
      const float4 f1 = *(const float4*)(b0 + d0 + 4);
      win[j][0] = f0.x; win[j][1] = f0.y; win[j][2] = f0.z; win[j][3] = f0.w;
      win[j][4] = f1.x; win[j][5] = f1.y; win[j][6] = f1.z; win[j][7] = f1.w;
    }
  }
  float s[5];
#pragma unroll
  for (int j = 0; j < 5; ++j) {
    float t = 0.f;
#pragma unroll
    for (int i = 0; i < 8; ++i) t += win[4][i] * win[j][i];
    s[j] = t;
  }
#pragma unroll
  for (int off = 1; off < 64; off <<= 1)
#pragma unroll
    for (int j = 0; j < 5; ++j) s[j] += __shfl_xor(s[j], off, 64);
  const float sc = 0.04419417382415922f;
  float mx = -1e30f;
#pragma unroll
  for (int j = 0; j < 5; ++j) { s[j] *= sc; mx = fmaxf(mx, s[j]); }
  float e[5], sum = 0.f;
#pragma unroll
  for (int j = 0; j < 5; ++j) { e[j] = __expf(s[j] - mx); sum += e[j]; }
  const float inv = 1.f / sum;
  __attribute__((ext_vector_type(8))) unsigned short o;
#pragma unroll
  for (int i = 0; i < 8; ++i) {
    float a = 0.f;
#pragma unroll
    for (int j = 0; j < 5; ++j) a += e[j] * win[j][i];
    o[i] = f2b(a * inv * outscale);
  }
  *(__attribute__((ext_vector_type(8))) unsigned short*)(out + (size_t)p * 512 + d0) = o;
}

// ----------------------------------------------------------------- attn ----
__global__ __launch_bounds__(256) void attn_k(const unsigned short* __restrict__ Q,
                                              const unsigned short* __restrict__ K,
                                              const unsigned short* __restrict__ V,
                                              unsigned short* __restrict__ AO) {
  __shared__ unsigned short Ks[2][64 * 64];
  __shared__ unsigned short Vt[2][64 * 64];
  const int tid = threadIdx.x;
  const int w = tid >> 6, l = tid & 63;
  const int lg = l >> 4, lr = l & 15;
  const int wg = (blockIdx.x & 7) * 256 + (blockIdx.x >> 3);
  const int qt = wg & 7, bh = wg >> 3;
  const int h = bh & 7, b = bh >> 3;
  const size_t base = (size_t)(b * 1024) * 512 + h * 64;
  const unsigned short* Qb = Q + base + (size_t)(qt * 128) * 512;
  const unsigned short* Kb = K + base;
  const unsigned short* Vb = V + base;

  bf16x8 qf[2][2];
#pragma unroll
  for (int rb = 0; rb < 2; ++rb)
#pragma unroll
    for (int ks = 0; ks < 2; ++ks)
      qf[rb][ks] = *(const bf16x8*)(Qb + (size_t)(w * 32 + rb * 16 + lr) * 512 + ks * 32 + lg * 8);

  f32x4 acc[2][4];
#pragma unroll
  for (int rb = 0; rb < 2; ++rb)
#pragma unroll
    for (int nb = 0; nb < 4; ++nb) acc[rb][nb] = (f32x4){0.f, 0.f, 0.f, 0.f};
  float lrun[2] = {0.f, 0.f};

  const int sk_row = tid >> 2, sk_seg = tid & 3;
  const int sv_key = tid & 63, sv_d0 = (tid >> 6) * 16;
  const int vpos = (sv_key & 32) + ((sv_key >> 2) & 3) * 8 + ((sv_key >> 4) & 1) * 4 + (sv_key & 3);
  const int vpg = vpos >> 3, vpw = vpos & 7;
  const int r7 = sk_row & 7;

  uint4 kr0, kr1, vr0, vr1;
  auto loadT = [&](int t) {
    const uint4* ksrc = (const uint4*)(Kb + (size_t)(t * 64 + sk_row) * 512 + sk_seg * 16);
    kr0 = ksrc[0]; kr1 = ksrc[1];
    const uint4* vsrc = (const uint4*)(Vb + (size_t)(t * 64 + sv_key) * 512 + sv_d0);
    vr0 = vsrc[0]; vr1 = vsrc[1];
  };
  auto writeT = [&](int bufi) {
    unsigned short* kd = Ks[bufi];
    unsigned short* vd = Vt[bufi];
    *(uint4*)&kd[sk_row * 64 + (((2 * sk_seg) ^ r7) << 3)] = kr0;
    *(uint4*)&kd[sk_row * 64 + (((2 * sk_seg + 1) ^ r7) << 3)] = kr1;
    const unsigned short* u0 = (const unsigned short*)&vr0;
    const unsigned short* u1 = (const unsigned short*)&vr1;
#pragma unroll
    for (int j = 0; j < 8; ++j) {
      vd[(sv_d0 + j) * 64 + (((vpg ^ j) << 3) | vpw)] = u0[j];
      vd[(sv_d0 + 8 + j) * 64 + (((vpg ^ j) << 3) | vpw)] = u1[j];
    }
  };

  loadT(0);
  writeT(0);
  loadT(1);
  barrier_lgkm();

  const int swz0 = (lg ^ (lr & 7)) << 3, swz1 = ((4 + lg) ^ (lr & 7)) << 3;

  for (int it = 0; it < 16; ++it) {
    const int cur = it & 1;
    f32x4 sf[2][4];
    __builtin_amdgcn_s_setprio(1);
#pragma unroll
    for (int kb = 0; kb < 4; ++kb) {
      const int krow = (kb * 16 + lr) * 64;
      bf16x8 kf0 = *(const bf16x8*)&Ks[cur][krow + swz0];
      bf16x8 kf1 = *(const bf16x8*)&Ks[cur][krow + swz1];
#pragma unroll
      for (int rb = 0; rb < 2; ++rb) {
        f32x4 z = (f32x4){0.f, 0.f, 0.f, 0.f};
        z = MFMA16(kf0, qf[rb][0], z);
        z = MFMA16(kf1, qf[rb][1], z);
        sf[rb][kb] = z;
      }
    }
    __builtin_amdgcn_s_setprio(0);

    if (it < 15) writeT((it + 1) & 1);
    if (it < 14) loadT(it + 2);

#pragma unroll
    for (int rb = 0; rb < 2; ++rb) {
#pragma unroll
      for (int kb = 0; kb < 4; ++kb)
#pragma unroll
        for (int r = 0; r < 4; ++r)
          sf[rb][kb][r] = __builtin_amdgcn_exp2f(sf[rb][kb][r]);
      float s0 = (sf[rb][0][0] + sf[rb][0][1]) + (sf[rb][0][2] + sf[rb][0][3]);
      float s1 = (sf[rb][1][0] + sf[rb][1][1]) + (sf[rb][1][2] + sf[rb][1][3]);
      float s2 = (sf[rb][2][0] + sf[rb][2][1]) + (sf[rb][2][2] + sf[rb][2][3]);
      float s3 = (sf[rb][3][0] + sf[rb][3][1]) + (sf[rb][3][2] + sf[rb][3][3]);
      float t = (s0 + s1) + (s2 + s3);
      t += __shfl_xor(t, 16, 64);
      t += __shfl_xor(t, 32, 64);
      lrun[rb] += t;
    }

    union { uint4 d; bf16x8 v; } pa[2][2];
#pragma unroll
    for (int rb = 0; rb < 2; ++rb)
#pragma unroll
      for (int t2 = 0; t2 < 2; ++t2) {
        pa[rb][t2].d.x = cvtpk(sf[rb][2 * t2][0], sf[rb][2 * t2][1]);
        pa[rb][t2].d.y = cvtpk(sf[rb][2 * t2][2], sf[rb][2 * t2][3]);
        pa[rb][t2].d.z = cvtpk(sf[rb][2 * t2 + 1][0], sf[rb][2 * t2 + 1][1]);
        pa[rb][t2].d.w = cvtpk(sf[rb][2 * t2 + 1][2], sf[rb][2 * t2 + 1][3]);
      }

    __builtin_amdgcn_s_setprio(1);
#pragma unroll
    for (int t2 = 0; t2 < 2; ++t2) {
      bf16x8 vf[4];
#pragma unroll
      for (int nb = 0; nb < 4; ++nb) {
        const int vrow = (nb * 16 + lr) * 64;
        vf[nb] = *(const bf16x8*)&Vt[cur][vrow + (((4 * t2 + lg) ^ (lr & 7)) << 3)];
      }
#pragma unroll
      for (int rb = 0; rb < 2; ++rb)
#pragma unroll
        for (int nb = 0; nb < 4; ++nb) acc[rb][nb] = MFMA16(pa[rb][t2].v, vf[nb], acc[rb][nb]);
    }
    __builtin_amdgcn_s_setprio(0);
    if (it < 15) barrier_lgkm();
  }

#pragma unroll
  for (int rb = 0; rb < 2; ++rb) {
    const float rec = 1.f / lrun[rb];
    float lv[4];
#pragma unroll
    for (int r = 0; r < 4; ++r) lv[r] = __shfl(rec, lg * 4 + r, 64);
#pragma unroll
    for (int nb = 0; nb < 4; ++nb) {
      const int gcol = nb * 16 + lr;
#pragma unroll
      for (int r = 0; r < 4; ++r) {
        const int grow = qt * 128 + w * 32 + rb * 16 + 4 * lg + r;
        AO[base + (size_t)grow * 512 + gcol] = f2b(acc[rb][nb][r] * lv[r]);
      }
    }
  }
}

// -------------------------------------------------------------- launch -----
extern "C" void kernel_launch(void* const* d_in, const int* in_sizes, int n_in,
                              void* d_out, int out_size, void* d_ws, size_t ws_size,
                              hipStream_t stream) {
  const float* query = (const float*)d_in[0];
  const float* key   = (const float*)d_in[1];
  const float* value = (const float*)d_in[2];
  const float* W0    = (const float*)d_in[3];
  const float* b0    = (const float*)d_in[4];
  const float* Wout  = (const float*)d_in[5];
  const float* bout  = (const float*)d_in[6];
  float* out = (float*)d_out;

  char* ws = (char*)d_ws;
  const size_t PSZ = (size_t)32768 * 512 * 2;
  unsigned short* Pq  = (unsigned short*)(ws);            // later reused as AO
  unsigned short* Pk  = (unsigned short*)(ws + PSZ);
  unsigned short* Pv  = (unsigned short*)(ws + 2 * PSZ);
  unsigned short* Qm  = (unsigned short*)(ws + 3 * PSZ);
  unsigned short* Km  = (unsigned short*)(ws + 4 * PSZ);
  unsigned short* W0T = (unsigned short*)(ws + 5 * PSZ);
  unsigned short* WoT = (unsigned short*)(ws + 5 * PSZ + 524288);

  tcast2_k<<<2048, 256, 0, stream>>>(W0, W0T, Wout, WoT);
  proj3_k<<<768, 512, 0, stream>>>(query, key, value, W0T, b0, Pq, Pk, Pv);
  localmix2_k<<<16384, 256, 0, stream>>>(Pq, Pk, b0, Qm, Km);
  attn_k<<<2048, 256, 0, stream>>>(Qm, Km, Pv, Pq /*AO*/);
  gemmout_k<<<256, 512, 0, stream>>>(Pq, WoT, bout, out);
}